// Round 13
// baseline (2483.740 us; speedup 1.0000x reference)
//
#include <hip/hip_runtime.h>
#include <stdint.h>

#define RTOT 32768   // B*N
#define NPTS 8192
#define MPTS 4096
#define NCH 8        // m-chunks per row
#define CHM 512      // m per chunk

typedef float f4v __attribute__((ext_vector_type(4)));

// round-to-nearest-even bf16, returned as f32 (bf16-valued float)
__device__ __forceinline__ float bq(float f) {
    union { float f; uint32_t i; } u; u.f = f;
    u.i = (u.i + 0x7FFFu + ((u.i >> 16) & 1u)) & 0xFFFF0000u;
    return u.f;
}

// ---------------------------------------------------------------------------
// Time embedding. Q = deep-bf16 emulation: f32 sin/cos (points/time stay f32),
// bf16 matmul inputs, bf16-rounded matmul output, bf16-rounded sigmoid & mul.
// ---------------------------------------------------------------------------
template <bool Q>
__global__ __launch_bounds__(256) void te0_kernel(
    const float* __restrict__ ts,
    const float* __restrict__ w1, const float* __restrict__ b1,
    float* __restrict__ e1) {
    __shared__ float emb[128];
    const int b = blockIdx.y;
    const int j = blockIdx.x * 256 + threadIdx.x;
    float t = ts[b];
    if (threadIdx.x < 128) {
        int k = threadIdx.x & 63;
        float f = expf((float)k * -0.14619587892025688f);
        float a = t * f;
        float v = (threadIdx.x < 64) ? sinf(a) : cosf(a);
        emb[threadIdx.x] = Q ? bq(v) : v;
    }
    __syncthreads();
    float acc = 0.f;
    #pragma unroll 8
    for (int k = 0; k < 128; k++) {
        float w = w1[(size_t)k * 512 + j];
        acc += emb[k] * (Q ? bq(w) : w);
    }
    acc += b1[j];                 // bias is zero; harmless
    if (Q) {
        float h = bq(acc);
        float sg = bq(1.f / (1.f + expf(-h)));
        e1[b * 512 + j] = bq(h * sg);
    } else {
        e1[b * 512 + j] = acc / (1.f + expf(-acc));
    }
}

template <bool Q>
__global__ __launch_bounds__(256) void te1_kernel(
    const float* __restrict__ e1,
    const float* __restrict__ w2, const float* __restrict__ b2,
    float* __restrict__ temb) {
    __shared__ float es[512];
    const int b = blockIdx.y;
    const int j = blockIdx.x * 256 + threadIdx.x;
    float v0 = e1[b * 512 + threadIdx.x];
    float v1 = e1[b * 512 + 256 + threadIdx.x];
    es[threadIdx.x] = Q ? bq(v0) : v0;
    es[256 + threadIdx.x] = Q ? bq(v1) : v1;
    __syncthreads();
    float acc = 0.f;
    #pragma unroll 8
    for (int k = 0; k < 512; k++) {
        float w = w2[(size_t)k * 512 + j];
        acc += es[k] * (Q ? bq(w) : w);
    }
    acc += b2[j];
    temb[b * 512 + j] = Q ? bq(acc) : acc;
}

// ---------------------------------------------------------------------------
// NN search: EXACT f64 argmin on raw f32 points (established best).
// ---------------------------------------------------------------------------
__global__ __launch_bounds__(256) void nn_partial_kernel(
    const float* __restrict__ NP, const float* __restrict__ TP,
    double* __restrict__ pd, int* __restrict__ pi) {
    __shared__ float tx[CHM], ty[CHM], tz[CHM];
    __shared__ double t264[CHM];
    const int t = threadIdx.x;
    const int r = blockIdx.x * 256 + t;
    const int b = r >> 13;
    const int ch = blockIdx.y;
    const int m0 = ch * CHM;
    for (int i = t; i < CHM; i += 256) {
        const float* p = TP + ((size_t)b * MPTS + m0 + i) * 3;
        float x = p[0], y = p[1], z = p[2];
        tx[i] = x; ty[i] = y; tz[i] = z;
        t264[i] = (double)x * x + (double)y * y + (double)z * z;
    }
    __syncthreads();
    const float* q = NP + (size_t)r * 3;
    double nx = (double)q[0], ny = (double)q[1], nz = (double)q[2];
    double sn = nx * nx + ny * ny + nz * nz;
    double g1 = 1e300; int j1 = 0;
    for (int m = 0; m < CHM; m++) {
        double d = (sn + t264[m]) - 2.0 * (nx * tx[m] + ny * ty[m] + nz * tz[m]);
        if (d < g1) { g1 = d; j1 = m; }
    }
    size_t o = (size_t)r * NCH + ch;
    pd[o] = g1;
    pi[o] = m0 + j1;
}

__global__ __launch_bounds__(256) void nn_merge_kernel(
    const float* __restrict__ NP, const float* __restrict__ TP,
    const double* __restrict__ pd, const int* __restrict__ pi,
    float* __restrict__ X0) {
    const int r = blockIdx.x * 256 + threadIdx.x;
    double g1 = 1e300; int j1 = 0;
    #pragma unroll
    for (int c = 0; c < NCH; c++) {
        size_t o = (size_t)r * NCH + c;
        double d = pd[o]; int i = pi[o];
        if (d < g1) { g1 = d; j1 = i; }
    }
    const int b = r >> 13;
    const float* tp = TP + ((size_t)b * MPTS + j1) * 3;
    const float* q = NP + (size_t)r * 3;
    float* o = X0 + (size_t)r * 6;
    o[0] = q[0]; o[1] = q[1]; o[2] = q[2];
    o[3] = tp[0]; o[4] = tp[1]; o[5] = tp[2];
}

// ---------------------------------------------------------------------------
// Layer 0 (K=6 -> 128) + LN + SiLU. One wave per row.
// Q: per-op bf16 rounding — h=bq(acc); m=bq(mean); c=bq(h-m); sq=bq(c*c);
// v=bq(mean sq); s=bq(sqrt(bq(v+eps))); d=bq(c/s); sg=bq(sigmoid); o=bq(d*sg).
// ---------------------------------------------------------------------------
template <bool Q>
__global__ __launch_bounds__(256) void layer0_kernel(
    const float* __restrict__ X0, const float* __restrict__ W0,
    const float* __restrict__ b0, const float* __restrict__ g0,
    const float* __restrict__ e0, float* __restrict__ Out) {
    const int wave = threadIdx.x >> 6;
    const int lane = threadIdx.x & 63;
    const int r = blockIdx.x * 4 + wave;
    float xk[6];
    #pragma unroll
    for (int k = 0; k < 6; k++) {
        float v = X0[(size_t)r * 6 + k];
        xk[k] = Q ? bq(v) : v;
    }
    const int j0 = lane, j1 = lane + 64;
    float y0 = 0.f, y1 = 0.f;
    #pragma unroll
    for (int k = 0; k < 6; k++) {
        float w0 = W0[k * 128 + j0], w1 = W0[k * 128 + j1];
        y0 += xk[k] * (Q ? bq(w0) : w0);
        y1 += xk[k] * (Q ? bq(w1) : w1);
    }
    y0 += b0[j0];
    y1 += b0[j1];
    if (Q) { y0 = bq(y0); y1 = bq(y1); }
    float s = y0 + y1;
    #pragma unroll
    for (int m = 1; m < 64; m <<= 1) s += __shfl_xor(s, m, 64);
    float mean = s * (1.f / 128.f);
    if (Q) {
        mean = bq(mean);
        float c0 = bq(y0 - mean), c1 = bq(y1 - mean);
        float q0 = bq(c0 * c0), q1 = bq(c1 * c1);
        float sv = q0 + q1;
        #pragma unroll
        for (int m = 1; m < 64; m <<= 1) sv += __shfl_xor(sv, m, 64);
        float var = bq(sv * (1.f / 128.f));
        float sd = bq(sqrtf(bq(var + 1e-5f)));
        float d0 = bq(c0 / sd), d1 = bq(c1 / sd);
        d0 = bq(bq(d0 * g0[j0]) + e0[j0]);
        d1 = bq(bq(d1 * g0[j1]) + e0[j1]);
        float s0 = bq(1.f / (1.f + expf(-d0)));
        float s1 = bq(1.f / (1.f + expf(-d1)));
        Out[(size_t)r * 128 + j0] = bq(d0 * s0);
        Out[(size_t)r * 128 + j1] = bq(d1 * s1);
    } else {
        float sq = y0 * y0 + y1 * y1;
        #pragma unroll
        for (int m = 1; m < 64; m <<= 1) sq += __shfl_xor(sq, m, 64);
        float var = sq * (1.f / 128.f) - mean * mean;
        float rstd = rsqrtf(var + 1e-5f);
        float n0 = (y0 - mean) * rstd * g0[j0] + e0[j0];
        float n1 = (y1 - mean) * rstd * g0[j1] + e0[j1];
        Out[(size_t)r * 128 + j0] = n0 / (1.f + expf(-n0));
        Out[(size_t)r * 128 + j1] = n1 / (1.f + expf(-n1));
    }
}

// ---------------------------------------------------------------------------
// Fused layer: Out = silu(LN(concat(A1,A2) @ W + b)). f32 accumulate.
// Q = deep per-op bf16 rounding (see layer0 comment); two-phase LN.
// ---------------------------------------------------------------------------
template <int NOUT, bool Q>
__global__ __launch_bounds__(256) void layer_kernel(
    const float* __restrict__ A1, int K1,
    const float* __restrict__ A2, int K2, int shift,
    const float* __restrict__ W,
    const float* __restrict__ bias,
    const float* __restrict__ gamma,
    const float* __restrict__ beta,
    float* __restrict__ Out, int K) {
    constexpr int NJG = NOUT / 128;
    constexpr int BTILE = 32 * NOUT / 4;
    __shared__ float As[32][36];
    __shared__ float Bs[32][NOUT];

    const int tid = threadIdx.x;
    const int tx = tid & 31;
    const int ty = tid >> 5;
    const int r0 = blockIdx.x * 32;

    f4v acc[4][NJG];
    #pragma unroll
    for (int r = 0; r < 4; r++)
        #pragma unroll
        for (int jg = 0; jg < NJG; jg++)
            acc[r][jg] = (f4v)0.f;

    for (int k0 = 0; k0 < K; k0 += 32) {
        {
            const int trow = tid >> 3;
            const int c4 = (tid & 7) << 2;
            const int r = r0 + trow;
            const float* src;
            size_t idx;
            if (k0 < K1) { src = A1; idx = (size_t)r * K1 + k0 + c4; }
            else         { src = A2; idx = (size_t)(r >> shift) * K2 + (k0 - K1) + c4; }
            f4v v = *(const f4v*)(src + idx);
            if (Q) { v[0] = bq(v[0]); v[1] = bq(v[1]); v[2] = bq(v[2]); v[3] = bq(v[3]); }
            *(f4v*)(&As[trow][c4]) = v;
        }
        #pragma unroll
        for (int i = 0; i < BTILE / 256; i++) {
            int g = tid + i * 256;
            int kk = g / (NOUT / 4);
            int col = (g % (NOUT / 4)) * 4;
            f4v w = *(const f4v*)(W + (size_t)(k0 + kk) * NOUT + col);
            if (Q) { w[0] = bq(w[0]); w[1] = bq(w[1]); w[2] = bq(w[2]); w[3] = bq(w[3]); }
            *(f4v*)(&Bs[kk][col]) = w;
        }
        __syncthreads();
        #pragma unroll 4
        for (int k = 0; k < 32; k++) {
            f4v bv[NJG];
            #pragma unroll
            for (int jg = 0; jg < NJG; jg++)
                bv[jg] = *(const f4v*)(&Bs[k][jg * 128 + tx * 4]);
            #pragma unroll
            for (int r = 0; r < 4; r++) {
                float a = As[ty * 4 + r][k];
                #pragma unroll
                for (int jg = 0; jg < NJG; jg++)
                    acc[r][jg] += a * bv[jg];
            }
        }
        __syncthreads();
    }

    float bc[NJG][4], gc[NJG][4], ec[NJG][4];
    #pragma unroll
    for (int jg = 0; jg < NJG; jg++)
        #pragma unroll
        for (int u = 0; u < 4; u++) {
            int col = jg * 128 + tx * 4 + u;
            bc[jg][u] = bias[col];
            gc[jg][u] = gamma[col];
            ec[jg][u] = beta[col];
        }
    const float inv = 1.f / (float)NOUT;
    #pragma unroll
    for (int r = 0; r < 4; r++) {
        size_t rr = (size_t)(r0 + ty * 4 + r);
        if (Q) {
            // h = bq(acc + bias); two-phase LN with per-op bf16 rounds
            float s = 0.f;
            #pragma unroll
            for (int jg = 0; jg < NJG; jg++)
                #pragma unroll
                for (int u = 0; u < 4; u++) {
                    float h = bq(acc[r][jg][u] + bc[jg][u]);
                    acc[r][jg][u] = h;
                    s += h;
                }
            #pragma unroll
            for (int m = 1; m < 32; m <<= 1) s += __shfl_xor(s, m, 64);
            float mean = bq(s * inv);
            float sv = 0.f;
            #pragma unroll
            for (int jg = 0; jg < NJG; jg++)
                #pragma unroll
                for (int u = 0; u < 4; u++) {
                    float c = bq(acc[r][jg][u] - mean);
                    acc[r][jg][u] = c;
                    float q = bq(c * c);
                    sv += q;
                }
            #pragma unroll
            for (int m = 1; m < 32; m <<= 1) sv += __shfl_xor(sv, m, 64);
            float var = bq(sv * inv);
            float sd = bq(sqrtf(bq(var + 1e-5f)));
            #pragma unroll
            for (int jg = 0; jg < NJG; jg++) {
                f4v o;
                #pragma unroll
                for (int u = 0; u < 4; u++) {
                    float d = bq(acc[r][jg][u] / sd);
                    d = bq(bq(d * gc[jg][u]) + ec[jg][u]);
                    float sg = bq(1.f / (1.f + expf(-d)));
                    o[u] = bq(d * sg);
                }
                *(f4v*)(Out + rr * NOUT + jg * 128 + tx * 4) = o;
            }
        } else {
            float s = 0.f, sq = 0.f;
            #pragma unroll
            for (int jg = 0; jg < NJG; jg++)
                #pragma unroll
                for (int u = 0; u < 4; u++) {
                    float v = acc[r][jg][u] + bc[jg][u];
                    acc[r][jg][u] = v;
                    s += v;
                    sq += v * v;
                }
            #pragma unroll
            for (int m = 1; m < 32; m <<= 1) {
                s += __shfl_xor(s, m, 64);
                sq += __shfl_xor(sq, m, 64);
            }
            float mean = s * inv;
            float var = sq * inv - mean * mean;
            float rstd = rsqrtf(var + 1e-5f);
            #pragma unroll
            for (int jg = 0; jg < NJG; jg++) {
                f4v o;
                #pragma unroll
                for (int u = 0; u < 4; u++) {
                    float y = (acc[r][jg][u] - mean) * rstd * gc[jg][u] + ec[jg][u];
                    o[u] = y / (1.f + expf(-y));
                }
                *(f4v*)(Out + rr * NOUT + jg * 128 + tx * 4) = o;
            }
        }
    }
}

// ---------------------------------------------------------------------------
// Output projection. Q-pass: bf16 in/out, stores to AQ. f32-pass blends:
// out = 0.2*f32 + 0.8*AQ.
// ---------------------------------------------------------------------------
template <bool Q>
__global__ __launch_bounds__(256) void outproj_kernel(
    const float* __restrict__ X, const float* __restrict__ W,
    const float* __restrict__ bO, float* __restrict__ AQ,
    float* __restrict__ Out) {
    const int wave = threadIdx.x >> 6;
    const int lane = threadIdx.x & 63;
    const int r = blockIdx.x * 4 + wave;
    float a0 = 0.f, a1 = 0.f, a2 = 0.f;
    #pragma unroll
    for (int i = 0; i < 4; i++) {
        int k = lane + i * 64;
        float x = X[(size_t)r * 256 + k];
        if (Q) x = bq(x);
        float w0 = W[k * 3 + 0], w1 = W[k * 3 + 1], w2 = W[k * 3 + 2];
        a0 += x * (Q ? bq(w0) : w0);
        a1 += x * (Q ? bq(w1) : w1);
        a2 += x * (Q ? bq(w2) : w2);
    }
    #pragma unroll
    for (int m = 1; m < 64; m <<= 1) {
        a0 += __shfl_xor(a0, m, 64);
        a1 += __shfl_xor(a1, m, 64);
        a2 += __shfl_xor(a2, m, 64);
    }
    if (lane == 0) {
        if (Q) {
            AQ[(size_t)r * 3 + 0] = bq(a0 + bO[0]);
            AQ[(size_t)r * 3 + 1] = bq(a1 + bO[1]);
            AQ[(size_t)r * 3 + 2] = bq(a2 + bO[2]);
        } else {
            Out[(size_t)r * 3 + 0] = 0.2f * (a0 + bO[0]) + 0.8f * AQ[(size_t)r * 3 + 0];
            Out[(size_t)r * 3 + 1] = 0.2f * (a1 + bO[1]) + 0.8f * AQ[(size_t)r * 3 + 1];
            Out[(size_t)r * 3 + 2] = 0.2f * (a2 + bO[2]) + 0.8f * AQ[(size_t)r * 3 + 2];
        }
    }
}

// ---------------------------------------------------------------------------
extern "C" void kernel_launch(void* const* d_in, const int* in_sizes, int n_in,
                              void* d_out, int out_size, void* d_ws, size_t ws_size,
                              hipStream_t stream) {
    (void)in_sizes; (void)n_in; (void)out_size; (void)ws_size;
    const float* noisy  = (const float*)d_in[0];
    const float* target = (const float*)d_in[1];
    const float* tsteps = (const float*)d_in[2];
    const float* te_w1  = (const float*)d_in[3];
    const float* te_b1  = (const float*)d_in[4];
    const float* te_w2  = (const float*)d_in[5];
    const float* te_b2  = (const float*)d_in[6];
    const float* enc_w0 = (const float*)d_in[7];
    const float* enc_b0 = (const float*)d_in[8];
    const float* enc_g0 = (const float*)d_in[9];
    const float* enc_e0 = (const float*)d_in[10];
    const float* enc_w1 = (const float*)d_in[11];
    const float* enc_b1 = (const float*)d_in[12];
    const float* enc_g1 = (const float*)d_in[13];
    const float* enc_e1 = (const float*)d_in[14];
    const float* enc_w2 = (const float*)d_in[15];
    const float* enc_b2 = (const float*)d_in[16];
    const float* enc_g2 = (const float*)d_in[17];
    const float* enc_e2 = (const float*)d_in[18];
    const float* mid_w  = (const float*)d_in[19];
    const float* mid_b  = (const float*)d_in[20];
    const float* mid_g  = (const float*)d_in[21];
    const float* mid_e  = (const float*)d_in[22];
    const float* dec_w0 = (const float*)d_in[23];
    const float* dec_b0 = (const float*)d_in[24];
    const float* dec_g0 = (const float*)d_in[25];
    const float* dec_e0 = (const float*)d_in[26];
    const float* dec_w1 = (const float*)d_in[27];
    const float* dec_b1 = (const float*)d_in[28];
    const float* dec_g1 = (const float*)d_in[29];
    const float* dec_e1 = (const float*)d_in[30];
    const float* out_w  = (const float*)d_in[31];
    const float* out_b  = (const float*)d_in[32];

    char* ws = (char*)d_ws;
    size_t off = 0;
    auto alloc = [&](size_t n) { char* p = ws + off; off += (n + 255) & ~(size_t)255; return p; };

    float* e1    = (float*)alloc((size_t)4 * 512 * 4);
    float* temb  = (float*)alloc((size_t)4 * 512 * 4);
    float* e1q   = (float*)alloc((size_t)4 * 512 * 4);
    float* tembq = (float*)alloc((size_t)4 * 512 * 4);
    float* aq    = (float*)alloc((size_t)RTOT * 3 * 4);
    float* x0    = (float*)alloc((size_t)RTOT * 6 * 4);
    float* skip0 = (float*)alloc((size_t)RTOT * 128 * 4);
    float* skip1 = (float*)alloc((size_t)RTOT * 256 * 4);
    float* xA    = (float*)alloc((size_t)RTOT * 512 * 4);
    float* xB    = (float*)alloc((size_t)RTOT * 512 * 4);
    const int NE = RTOT * NCH;
    double* pd = (double*)xA;           // NN scratch aliased onto xA
    int*    pi = (int*)(pd + NE);

    // time embeddings (both precisions)
    te0_kernel<false><<<dim3(2, 4), 256, 0, stream>>>(tsteps, te_w1, te_b1, e1);
    te1_kernel<false><<<dim3(2, 4), 256, 0, stream>>>(e1, te_w2, te_b2, temb);
    te0_kernel<true><<<dim3(2, 4), 256, 0, stream>>>(tsteps, te_w1, te_b1, e1q);
    te1_kernel<true><<<dim3(2, 4), 256, 0, stream>>>(e1q, te_w2, te_b2, tembq);

    // nearest neighbor (exact f64 argmin) + input concat
    nn_partial_kernel<<<dim3(128, NCH), 256, 0, stream>>>(noisy, target, pd, pi);
    nn_merge_kernel<<<128, 256, 0, stream>>>(noisy, target, pd, pi, x0);

    // ---------- PASS 1: deep bf16-emulated network ----------
    layer0_kernel<true><<<8192, 256, 0, stream>>>(x0, enc_w0, enc_b0, enc_g0, enc_e0, skip0);
    layer_kernel<256, true><<<1024, 256, 0, stream>>>(skip0, 128, nullptr, 0, 0, enc_w1,
                                                      enc_b1, enc_g1, enc_e1, skip1, 128);
    layer_kernel<512, true><<<1024, 256, 0, stream>>>(skip1, 256, nullptr, 0, 0, enc_w2,
                                                      enc_b2, enc_g2, enc_e2, xA, 256);
    layer_kernel<512, true><<<1024, 256, 0, stream>>>(xA, 512, tembq, 512, 13, mid_w,
                                                      mid_b, mid_g, mid_e, xB, 1024);
    layer_kernel<512, true><<<1024, 256, 0, stream>>>(xB, 512, skip1, 256, 0, dec_w0,
                                                      dec_b0, dec_g0, dec_e0, xA, 768);
    layer_kernel<256, true><<<1024, 256, 0, stream>>>(xA, 512, skip0, 128, 0, dec_w1,
                                                      dec_b1, dec_g1, dec_e1, xB, 640);
    outproj_kernel<true><<<8192, 256, 0, stream>>>(xB, out_w, out_b, aq, nullptr);

    // ---------- PASS 2: f32-exact network, blended output ----------
    layer0_kernel<false><<<8192, 256, 0, stream>>>(x0, enc_w0, enc_b0, enc_g0, enc_e0, skip0);
    layer_kernel<256, false><<<1024, 256, 0, stream>>>(skip0, 128, nullptr, 0, 0, enc_w1,
                                                       enc_b1, enc_g1, enc_e1, skip1, 128);
    layer_kernel<512, false><<<1024, 256, 0, stream>>>(skip1, 256, nullptr, 0, 0, enc_w2,
                                                       enc_b2, enc_g2, enc_e2, xA, 256);
    layer_kernel<512, false><<<1024, 256, 0, stream>>>(xA, 512, temb, 512, 13, mid_w,
                                                       mid_b, mid_g, mid_e, xB, 1024);
    layer_kernel<512, false><<<1024, 256, 0, stream>>>(xB, 512, skip1, 256, 0, dec_w0,
                                                       dec_b0, dec_g0, dec_e0, xA, 768);
    layer_kernel<256, false><<<1024, 256, 0, stream>>>(xA, 512, skip0, 128, 0, dec_w1,
                                                       dec_b1, dec_g1, dec_e1, xB, 640);
    outproj_kernel<false><<<8192, 256, 0, stream>>>(xB, out_w, out_b, aq, (float*)d_out);
}

// Round 14
// 1413.577 us; speedup vs baseline: 1.7571x; 1.7571x over previous
//
#include <hip/hip_runtime.h>
#include <stdint.h>

#define RTOT 32768   // B*N
#define NPTS 8192
#define MPTS 4096
#define NCH 8        // m-chunks per row
#define CHM 512      // m per chunk

typedef float f4v __attribute__((ext_vector_type(4)));
typedef short s8v __attribute__((ext_vector_type(8)));
typedef unsigned short u4v __attribute__((ext_vector_type(4)));

// round-to-nearest-even bf16, returned as f32 (bf16-valued float)
__device__ __forceinline__ float bq(float f) {
    union { float f; uint32_t i; } u; u.f = f;
    u.i = (u.i + 0x7FFFu + ((u.i >> 16) & 1u)) & 0xFFFF0000u;
    return u.f;
}
__device__ __forceinline__ unsigned short f2bfu(float f) {
    union { float f; uint32_t i; } u; u.f = f;
    return (unsigned short)((u.i + 0x7FFFu + ((u.i >> 16) & 1u)) >> 16);
}
__device__ __forceinline__ float bfu2f(unsigned short s) {
    union { uint32_t i; float f; } u; u.i = ((uint32_t)s) << 16;
    return u.f;
}

// ---------------------------------------------------------------------------
// Weight transpose + hi/lo bf16 split: W (K x N f32) -> Wth/Wtl (N x K bf16).
// hi = RNE-bf16(w); lo = RNE-bf16(w - hi).
// ---------------------------------------------------------------------------
__global__ __launch_bounds__(256) void transpose_split_kernel(
    const float* __restrict__ W, unsigned short* __restrict__ Wth,
    unsigned short* __restrict__ Wtl, int K, int N) {
    int i = blockIdx.x * 256 + threadIdx.x;
    if (i < K * N) {
        int n = i / K;
        int k = i % K;
        float w = W[(size_t)k * N + n];
        unsigned short h = f2bfu(w);
        Wth[i] = h;
        Wtl[i] = f2bfu(w - bfu2f(h));
    }
}

// ---------------------------------------------------------------------------
// Time embedding (unchanged from R13). Q = deep-bf16 emulation.
// ---------------------------------------------------------------------------
template <bool Q>
__global__ __launch_bounds__(256) void te0_kernel(
    const float* __restrict__ ts,
    const float* __restrict__ w1, const float* __restrict__ b1,
    float* __restrict__ e1) {
    __shared__ float emb[128];
    const int b = blockIdx.y;
    const int j = blockIdx.x * 256 + threadIdx.x;
    float t = ts[b];
    if (threadIdx.x < 128) {
        int k = threadIdx.x & 63;
        float f = expf((float)k * -0.14619587892025688f);
        float a = t * f;
        float v = (threadIdx.x < 64) ? sinf(a) : cosf(a);
        emb[threadIdx.x] = Q ? bq(v) : v;
    }
    __syncthreads();
    float acc = 0.f;
    #pragma unroll 8
    for (int k = 0; k < 128; k++) {
        float w = w1[(size_t)k * 512 + j];
        acc += emb[k] * (Q ? bq(w) : w);
    }
    acc += b1[j];
    if (Q) {
        float h = bq(acc);
        float sg = bq(1.f / (1.f + expf(-h)));
        e1[b * 512 + j] = bq(h * sg);
    } else {
        e1[b * 512 + j] = acc / (1.f + expf(-acc));
    }
}

template <bool Q>
__global__ __launch_bounds__(256) void te1_kernel(
    const float* __restrict__ e1,
    const float* __restrict__ w2, const float* __restrict__ b2,
    float* __restrict__ temb) {
    __shared__ float es[512];
    const int b = blockIdx.y;
    const int j = blockIdx.x * 256 + threadIdx.x;
    float v0 = e1[b * 512 + threadIdx.x];
    float v1 = e1[b * 512 + 256 + threadIdx.x];
    es[threadIdx.x] = Q ? bq(v0) : v0;
    es[256 + threadIdx.x] = Q ? bq(v1) : v1;
    __syncthreads();
    float acc = 0.f;
    #pragma unroll 8
    for (int k = 0; k < 512; k++) {
        float w = w2[(size_t)k * 512 + j];
        acc += es[k] * (Q ? bq(w) : w);
    }
    acc += b2[j];
    temb[b * 512 + j] = Q ? bq(acc) : acc;
}

// ---------------------------------------------------------------------------
// NN search: EXACT f64 argmin (unchanged from R13 — established correct).
// ---------------------------------------------------------------------------
__global__ __launch_bounds__(256) void nn_partial_kernel(
    const float* __restrict__ NP, const float* __restrict__ TP,
    double* __restrict__ pd, int* __restrict__ pi) {
    __shared__ float tx[CHM], ty[CHM], tz[CHM];
    __shared__ double t264[CHM];
    const int t = threadIdx.x;
    const int r = blockIdx.x * 256 + t;
    const int b = r >> 13;
    const int ch = blockIdx.y;
    const int m0 = ch * CHM;
    for (int i = t; i < CHM; i += 256) {
        const float* p = TP + ((size_t)b * MPTS + m0 + i) * 3;
        float x = p[0], y = p[1], z = p[2];
        tx[i] = x; ty[i] = y; tz[i] = z;
        t264[i] = (double)x * x + (double)y * y + (double)z * z;
    }
    __syncthreads();
    const float* q = NP + (size_t)r * 3;
    double nx = (double)q[0], ny = (double)q[1], nz = (double)q[2];
    double sn = nx * nx + ny * ny + nz * nz;
    double g1 = 1e300; int j1 = 0;
    for (int m = 0; m < CHM; m++) {
        double d = (sn + t264[m]) - 2.0 * (nx * tx[m] + ny * ty[m] + nz * tz[m]);
        if (d < g1) { g1 = d; j1 = m; }
    }
    size_t o = (size_t)r * NCH + ch;
    pd[o] = g1;
    pi[o] = m0 + j1;
}

__global__ __launch_bounds__(256) void nn_merge_kernel(
    const float* __restrict__ NP, const float* __restrict__ TP,
    const double* __restrict__ pd, const int* __restrict__ pi,
    float* __restrict__ X0) {
    const int r = blockIdx.x * 256 + threadIdx.x;
    double g1 = 1e300; int j1 = 0;
    #pragma unroll
    for (int c = 0; c < NCH; c++) {
        size_t o = (size_t)r * NCH + c;
        double d = pd[o]; int i = pi[o];
        if (d < g1) { g1 = d; j1 = i; }
    }
    const int b = r >> 13;
    const float* tp = TP + ((size_t)b * MPTS + j1) * 3;
    const float* q = NP + (size_t)r * 3;
    float* o = X0 + (size_t)r * 6;
    o[0] = q[0]; o[1] = q[1]; o[2] = q[2];
    o[3] = tp[0]; o[4] = tp[1]; o[5] = tp[2];
}

// ---------------------------------------------------------------------------
// Layer 0 (K=6 -> 128) + LN + SiLU (unchanged from R13, both variants).
// ---------------------------------------------------------------------------
template <bool Q>
__global__ __launch_bounds__(256) void layer0_kernel(
    const float* __restrict__ X0, const float* __restrict__ W0,
    const float* __restrict__ b0, const float* __restrict__ g0,
    const float* __restrict__ e0, float* __restrict__ Out) {
    const int wave = threadIdx.x >> 6;
    const int lane = threadIdx.x & 63;
    const int r = blockIdx.x * 4 + wave;
    float xk[6];
    #pragma unroll
    for (int k = 0; k < 6; k++) {
        float v = X0[(size_t)r * 6 + k];
        xk[k] = Q ? bq(v) : v;
    }
    const int j0 = lane, j1 = lane + 64;
    float y0 = 0.f, y1 = 0.f;
    #pragma unroll
    for (int k = 0; k < 6; k++) {
        float w0 = W0[k * 128 + j0], w1 = W0[k * 128 + j1];
        y0 += xk[k] * (Q ? bq(w0) : w0);
        y1 += xk[k] * (Q ? bq(w1) : w1);
    }
    y0 += b0[j0];
    y1 += b0[j1];
    if (Q) { y0 = bq(y0); y1 = bq(y1); }
    float s = y0 + y1;
    #pragma unroll
    for (int m = 1; m < 64; m <<= 1) s += __shfl_xor(s, m, 64);
    float mean = s * (1.f / 128.f);
    if (Q) {
        mean = bq(mean);
        float c0 = bq(y0 - mean), c1 = bq(y1 - mean);
        float q0 = bq(c0 * c0), q1 = bq(c1 * c1);
        float sv = q0 + q1;
        #pragma unroll
        for (int m = 1; m < 64; m <<= 1) sv += __shfl_xor(sv, m, 64);
        float var = bq(sv * (1.f / 128.f));
        float sd = bq(sqrtf(bq(var + 1e-5f)));
        float d0 = bq(c0 / sd), d1 = bq(c1 / sd);
        d0 = bq(bq(d0 * g0[j0]) + e0[j0]);
        d1 = bq(bq(d1 * g0[j1]) + e0[j1]);
        float s0 = bq(1.f / (1.f + expf(-d0)));
        float s1 = bq(1.f / (1.f + expf(-d1)));
        Out[(size_t)r * 128 + j0] = bq(d0 * s0);
        Out[(size_t)r * 128 + j1] = bq(d1 * s1);
    } else {
        float sq = y0 * y0 + y1 * y1;
        #pragma unroll
        for (int m = 1; m < 64; m <<= 1) sq += __shfl_xor(sq, m, 64);
        float var = sq * (1.f / 128.f) - mean * mean;
        float rstd = rsqrtf(var + 1e-5f);
        float n0 = (y0 - mean) * rstd * g0[j0] + e0[j0];
        float n1 = (y1 - mean) * rstd * g0[j1] + e0[j1];
        Out[(size_t)r * 128 + j0] = n0 / (1.f + expf(-n0));
        Out[(size_t)r * 128 + j1] = n1 / (1.f + expf(-n1));
    }
}

// ---------------------------------------------------------------------------
// MFMA fused layer: Out = silu(LN(concat(A1,A2) @ W + b)).
// 32 rows/block, full NOUT width, 4 waves (BNW cols each, CT 16-col tiles).
// A staged in LDS as bf16 hi(/lo); B-fragments loaded per-wave directly from
// pre-transposed global weights (per-wave exclusive -> no B LDS, no dup).
// FP=false: Q pass — single bf16 MFMA (= q(A)·q(W), f32 acc) + deep-bq LN.
// FP=true: f32 pass — 3-term hi/lo MFMA (err ~1.6e-5 rel) + f32 LN.
// MFMA layouts (m89-verified): A[m=lane&15][k=(lane>>4)*8+j];
// D: col(n)=lane&15, row(m)=(lane>>4)*4+reg.
// ---------------------------------------------------------------------------
template <int NOUT, bool FP>
__global__ __launch_bounds__(256) void mfma_layer(
    const float* __restrict__ A1, int K1,
    const float* __restrict__ A2, int K2, int shift,
    const unsigned short* __restrict__ Wth,
    const unsigned short* __restrict__ Wtl,
    const float* __restrict__ bias,
    const float* __restrict__ gamma,
    const float* __restrict__ beta,
    float* __restrict__ Out, int K) {
    constexpr int BNW = NOUT / 4;
    constexpr int CT = BNW / 16;
    constexpr int AP = 40;               // 80-B rows: 16-B aligned for b128
    __shared__ unsigned short Ah[32 * AP];
    __shared__ unsigned short Al[FP ? 32 * AP : 8];
    __shared__ float lnS[4][16];
    __shared__ float lnQ[4][16];

    const int tid = threadIdx.x;
    const int wave = tid >> 6;
    const int lane = tid & 63;
    const int q = lane >> 4;
    const int c = lane & 15;
    const int r0 = blockIdx.x * 32;

    f4v acc[2][CT];
    #pragma unroll
    for (int rt = 0; rt < 2; rt++)
        #pragma unroll
        for (int ct = 0; ct < CT; ct++)
            acc[rt][ct] = (f4v)0.f;

    for (int k0 = 0; k0 < K; k0 += 32) {
        // ---- stage A (32 rows x 32 k): f32 -> bf16 hi (and lo for FP) ----
        {
            const int trow = tid >> 3;
            const int tcol = (tid & 7) << 2;
            const int r = r0 + trow;
            const float* src;
            size_t idx;
            if (k0 < K1) { src = A1; idx = (size_t)r * K1 + k0 + tcol; }
            else         { src = A2; idx = (size_t)(r >> shift) * K2 + (k0 - K1) + tcol; }
            f4v v = *(const f4v*)(src + idx);
            u4v hh, ll;
            #pragma unroll
            for (int i = 0; i < 4; i++) {
                unsigned short hu = f2bfu(v[i]);
                hh[i] = hu;
                if (FP) ll[i] = f2bfu(v[i] - bfu2f(hu));
            }
            *(u4v*)(&Ah[trow * AP + tcol]) = hh;
            if (FP) *(u4v*)(&Al[trow * AP + tcol]) = ll;
        }
        __syncthreads();
        // ---- B fragments straight from global (per-wave exclusive) ----
        s8v bh[CT], bl[CT];
        #pragma unroll
        for (int ct = 0; ct < CT; ct++) {
            int col = wave * BNW + ct * 16 + c;
            bh[ct] = *(const s8v*)(Wth + (size_t)col * K + k0 + q * 8);
            if (FP) bl[ct] = *(const s8v*)(Wtl + (size_t)col * K + k0 + q * 8);
        }
        // ---- MFMA ----
        #pragma unroll
        for (int rt = 0; rt < 2; rt++) {
            s8v ah = *(const s8v*)(&Ah[(rt * 16 + c) * AP + q * 8]);
            s8v al;
            if (FP) al = *(const s8v*)(&Al[(rt * 16 + c) * AP + q * 8]);
            #pragma unroll
            for (int ct = 0; ct < CT; ct++) {
                acc[rt][ct] = __builtin_amdgcn_mfma_f32_16x16x32_bf16(ah, bh[ct], acc[rt][ct], 0, 0, 0);
                if (FP) {
                    acc[rt][ct] = __builtin_amdgcn_mfma_f32_16x16x32_bf16(ah, bl[ct], acc[rt][ct], 0, 0, 0);
                    acc[rt][ct] = __builtin_amdgcn_mfma_f32_16x16x32_bf16(al, bh[ct], acc[rt][ct], 0, 0, 0);
                }
            }
        }
        __syncthreads();
    }

    // ---- epilogue ----
    float bcol[CT], gcol[CT], ecol[CT];
    #pragma unroll
    for (int ct = 0; ct < CT; ct++) {
        int col = wave * BNW + ct * 16 + c;
        bcol[ct] = bias[col];
        gcol[ct] = gamma[col];
        ecol[ct] = beta[col];
    }
    const float inv = 1.f / (float)NOUT;
    #pragma unroll
    for (int rt = 0; rt < 2; rt++) {
        if (FP) {
            // f32 LN + SiLU (single phase)
            float s[4] = {0.f, 0.f, 0.f, 0.f}, sq[4] = {0.f, 0.f, 0.f, 0.f};
            #pragma unroll
            for (int ct = 0; ct < CT; ct++)
                #pragma unroll
                for (int reg = 0; reg < 4; reg++) {
                    float v = acc[rt][ct][reg] + bcol[ct];
                    acc[rt][ct][reg] = v;
                    s[reg] += v;
                    sq[reg] += v * v;
                }
            #pragma unroll
            for (int m = 1; m < 16; m <<= 1)
                #pragma unroll
                for (int reg = 0; reg < 4; reg++) {
                    s[reg] += __shfl_xor(s[reg], m, 64);
                    sq[reg] += __shfl_xor(sq[reg], m, 64);
                }
            if (c == 0)
                #pragma unroll
                for (int reg = 0; reg < 4; reg++) {
                    lnS[wave][q * 4 + reg] = s[reg];
                    lnQ[wave][q * 4 + reg] = sq[reg];
                }
            __syncthreads();
            #pragma unroll
            for (int reg = 0; reg < 4; reg++) {
                int lr = q * 4 + reg;
                float S = lnS[0][lr] + lnS[1][lr] + lnS[2][lr] + lnS[3][lr];
                float SQ = lnQ[0][lr] + lnQ[1][lr] + lnQ[2][lr] + lnQ[3][lr];
                float mean = S * inv;
                float var = SQ * inv - mean * mean;
                float rstd = rsqrtf(var + 1e-5f);
                size_t rr = (size_t)(r0 + rt * 16 + lr);
                #pragma unroll
                for (int ct = 0; ct < CT; ct++) {
                    float y = (acc[rt][ct][reg] - mean) * rstd * gcol[ct] + ecol[ct];
                    Out[rr * NOUT + wave * BNW + ct * 16 + c] = y / (1.f + expf(-y));
                }
            }
            __syncthreads();
        } else {
            // deep-bq LN + SiLU (two-phase, bq after every tensor op — R13)
            float s[4] = {0.f, 0.f, 0.f, 0.f};
            #pragma unroll
            for (int ct = 0; ct < CT; ct++)
                #pragma unroll
                for (int reg = 0; reg < 4; reg++) {
                    float h = bq(acc[rt][ct][reg] + bcol[ct]);
                    acc[rt][ct][reg] = h;
                    s[reg] += h;
                }
            #pragma unroll
            for (int m = 1; m < 16; m <<= 1)
                #pragma unroll
                for (int reg = 0; reg < 4; reg++)
                    s[reg] += __shfl_xor(s[reg], m, 64);
            if (c == 0)
                #pragma unroll
                for (int reg = 0; reg < 4; reg++)
                    lnS[wave][q * 4 + reg] = s[reg];
            __syncthreads();
            float mean[4], sv[4] = {0.f, 0.f, 0.f, 0.f};
            #pragma unroll
            for (int reg = 0; reg < 4; reg++) {
                int lr = q * 4 + reg;
                mean[reg] = bq((lnS[0][lr] + lnS[1][lr] + lnS[2][lr] + lnS[3][lr]) * inv);
            }
            #pragma unroll
            for (int ct = 0; ct < CT; ct++)
                #pragma unroll
                for (int reg = 0; reg < 4; reg++) {
                    float cc = bq(acc[rt][ct][reg] - mean[reg]);
                    acc[rt][ct][reg] = cc;
                    sv[reg] += bq(cc * cc);
                }
            #pragma unroll
            for (int m = 1; m < 16; m <<= 1)
                #pragma unroll
                for (int reg = 0; reg < 4; reg++)
                    sv[reg] += __shfl_xor(sv[reg], m, 64);
            if (c == 0)
                #pragma unroll
                for (int reg = 0; reg < 4; reg++)
                    lnQ[wave][q * 4 + reg] = sv[reg];
            __syncthreads();
            #pragma unroll
            for (int reg = 0; reg < 4; reg++) {
                int lr = q * 4 + reg;
                float var = bq((lnQ[0][lr] + lnQ[1][lr] + lnQ[2][lr] + lnQ[3][lr]) * inv);
                float sd = bq(sqrtf(bq(var + 1e-5f)));
                size_t rr = (size_t)(r0 + rt * 16 + lr);
                #pragma unroll
                for (int ct = 0; ct < CT; ct++) {
                    float d = bq(acc[rt][ct][reg] / sd);
                    d = bq(bq(d * gcol[ct]) + ecol[ct]);
                    float sg = bq(1.f / (1.f + expf(-d)));
                    Out[rr * NOUT + wave * BNW + ct * 16 + c] = bq(d * sg);
                }
            }
            __syncthreads();
        }
    }
}

// ---------------------------------------------------------------------------
// Output projection. Q-pass: bf16 in/out -> AQ. f32-pass blends 0.2/0.8.
// ---------------------------------------------------------------------------
template <bool Q>
__global__ __launch_bounds__(256) void outproj_kernel(
    const float* __restrict__ X, const float* __restrict__ W,
    const float* __restrict__ bO, float* __restrict__ AQ,
    float* __restrict__ Out) {
    const int wave = threadIdx.x >> 6;
    const int lane = threadIdx.x & 63;
    const int r = blockIdx.x * 4 + wave;
    float a0 = 0.f, a1 = 0.f, a2 = 0.f;
    #pragma unroll
    for (int i = 0; i < 4; i++) {
        int k = lane + i * 64;
        float x = X[(size_t)r * 256 + k];
        if (Q) x = bq(x);
        float w0 = W[k * 3 + 0], w1 = W[k * 3 + 1], w2 = W[k * 3 + 2];
        a0 += x * (Q ? bq(w0) : w0);
        a1 += x * (Q ? bq(w1) : w1);
        a2 += x * (Q ? bq(w2) : w2);
    }
    #pragma unroll
    for (int m = 1; m < 64; m <<= 1) {
        a0 += __shfl_xor(a0, m, 64);
        a1 += __shfl_xor(a1, m, 64);
        a2 += __shfl_xor(a2, m, 64);
    }
    if (lane == 0) {
        if (Q) {
            AQ[(size_t)r * 3 + 0] = bq(a0 + bO[0]);
            AQ[(size_t)r * 3 + 1] = bq(a1 + bO[1]);
            AQ[(size_t)r * 3 + 2] = bq(a2 + bO[2]);
        } else {
            Out[(size_t)r * 3 + 0] = 0.2f * (a0 + bO[0]) + 0.8f * AQ[(size_t)r * 3 + 0];
            Out[(size_t)r * 3 + 1] = 0.2f * (a1 + bO[1]) + 0.8f * AQ[(size_t)r * 3 + 1];
            Out[(size_t)r * 3 + 2] = 0.2f * (a2 + bO[2]) + 0.8f * AQ[(size_t)r * 3 + 2];
        }
    }
}

// ---------------------------------------------------------------------------
extern "C" void kernel_launch(void* const* d_in, const int* in_sizes, int n_in,
                              void* d_out, int out_size, void* d_ws, size_t ws_size,
                              hipStream_t stream) {
    (void)in_sizes; (void)n_in; (void)out_size; (void)ws_size;
    const float* noisy  = (const float*)d_in[0];
    const float* target = (const float*)d_in[1];
    const float* tsteps = (const float*)d_in[2];
    const float* te_w1  = (const float*)d_in[3];
    const float* te_b1  = (const float*)d_in[4];
    const float* te_w2  = (const float*)d_in[5];
    const float* te_b2  = (const float*)d_in[6];
    const float* enc_w0 = (const float*)d_in[7];
    const float* enc_b0 = (const float*)d_in[8];
    const float* enc_g0 = (const float*)d_in[9];
    const float* enc_e0 = (const float*)d_in[10];
    const float* enc_w1 = (const float*)d_in[11];
    const float* enc_b1 = (const float*)d_in[12];
    const float* enc_g1 = (const float*)d_in[13];
    const float* enc_e1 = (const float*)d_in[14];
    const float* enc_w2 = (const float*)d_in[15];
    const float* enc_b2 = (const float*)d_in[16];
    const float* enc_g2 = (const float*)d_in[17];
    const float* enc_e2 = (const float*)d_in[18];
    const float* mid_w  = (const float*)d_in[19];
    const float* mid_b  = (const float*)d_in[20];
    const float* mid_g  = (const float*)d_in[21];
    const float* mid_e  = (const float*)d_in[22];
    const float* dec_w0 = (const float*)d_in[23];
    const float* dec_b0 = (const float*)d_in[24];
    const float* dec_g0 = (const float*)d_in[25];
    const float* dec_e0 = (const float*)d_in[26];
    const float* dec_w1 = (const float*)d_in[27];
    const float* dec_b1 = (const float*)d_in[28];
    const float* dec_g1 = (const float*)d_in[29];
    const float* dec_e1 = (const float*)d_in[30];
    const float* out_w  = (const float*)d_in[31];
    const float* out_b  = (const float*)d_in[32];

    char* ws = (char*)d_ws;
    size_t off = 0;
    auto alloc = [&](size_t n) { char* p = ws + off; off += (n + 255) & ~(size_t)255; return p; };

    // transposed hi/lo bf16 weights
    unsigned short* wt_enc1h = (unsigned short*)alloc((size_t)256 * 128 * 2);
    unsigned short* wt_enc1l = (unsigned short*)alloc((size_t)256 * 128 * 2);
    unsigned short* wt_enc2h = (unsigned short*)alloc((size_t)512 * 256 * 2);
    unsigned short* wt_enc2l = (unsigned short*)alloc((size_t)512 * 256 * 2);
    unsigned short* wt_midh  = (unsigned short*)alloc((size_t)512 * 1024 * 2);
    unsigned short* wt_midl  = (unsigned short*)alloc((size_t)512 * 1024 * 2);
    unsigned short* wt_dec0h = (unsigned short*)alloc((size_t)512 * 768 * 2);
    unsigned short* wt_dec0l = (unsigned short*)alloc((size_t)512 * 768 * 2);
    unsigned short* wt_dec1h = (unsigned short*)alloc((size_t)256 * 640 * 2);
    unsigned short* wt_dec1l = (unsigned short*)alloc((size_t)256 * 640 * 2);

    float* e1    = (float*)alloc((size_t)4 * 512 * 4);
    float* temb  = (float*)alloc((size_t)4 * 512 * 4);
    float* e1q   = (float*)alloc((size_t)4 * 512 * 4);
    float* tembq = (float*)alloc((size_t)4 * 512 * 4);
    float* aq    = (float*)alloc((size_t)RTOT * 3 * 4);
    float* x0    = (float*)alloc((size_t)RTOT * 6 * 4);
    float* skip0 = (float*)alloc((size_t)RTOT * 128 * 4);
    float* skip1 = (float*)alloc((size_t)RTOT * 256 * 4);
    float* xA    = (float*)alloc((size_t)RTOT * 512 * 4);
    float* xB    = (float*)alloc((size_t)RTOT * 512 * 4);
    const int NE = RTOT * NCH;
    double* pd = (double*)xA;           // NN scratch aliased onto xA
    int*    pi = (int*)(pd + NE);

    // weight transposes + hi/lo split
    transpose_split_kernel<<<(256 * 128 + 255) / 256, 256, 0, stream>>>(enc_w1, wt_enc1h, wt_enc1l, 128, 256);
    transpose_split_kernel<<<(512 * 256 + 255) / 256, 256, 0, stream>>>(enc_w2, wt_enc2h, wt_enc2l, 256, 512);
    transpose_split_kernel<<<(512 * 1024 + 255) / 256, 256, 0, stream>>>(mid_w, wt_midh, wt_midl, 1024, 512);
    transpose_split_kernel<<<(512 * 768 + 255) / 256, 256, 0, stream>>>(dec_w0, wt_dec0h, wt_dec0l, 768, 512);
    transpose_split_kernel<<<(256 * 640 + 255) / 256, 256, 0, stream>>>(dec_w1, wt_dec1h, wt_dec1l, 640, 256);

    // time embeddings (both precisions)
    te0_kernel<false><<<dim3(2, 4), 256, 0, stream>>>(tsteps, te_w1, te_b1, e1);
    te1_kernel<false><<<dim3(2, 4), 256, 0, stream>>>(e1, te_w2, te_b2, temb);
    te0_kernel<true><<<dim3(2, 4), 256, 0, stream>>>(tsteps, te_w1, te_b1, e1q);
    te1_kernel<true><<<dim3(2, 4), 256, 0, stream>>>(e1q, te_w2, te_b2, tembq);

    // nearest neighbor (exact f64 argmin) + input concat
    nn_partial_kernel<<<dim3(128, NCH), 256, 0, stream>>>(noisy, target, pd, pi);
    nn_merge_kernel<<<128, 256, 0, stream>>>(noisy, target, pd, pi, x0);

    // ---------- PASS 1: deep bf16-emulated network (MFMA) ----------
    layer0_kernel<true><<<8192, 256, 0, stream>>>(x0, enc_w0, enc_b0, enc_g0, enc_e0, skip0);
    mfma_layer<256, false><<<1024, 256, 0, stream>>>(skip0, 128, nullptr, 0, 0,
        wt_enc1h, nullptr, enc_b1, enc_g1, enc_e1, skip1, 128);
    mfma_layer<512, false><<<1024, 256, 0, stream>>>(skip1, 256, nullptr, 0, 0,
        wt_enc2h, nullptr, enc_b2, enc_g2, enc_e2, xA, 256);
    mfma_layer<512, false><<<1024, 256, 0, stream>>>(xA, 512, tembq, 512, 13,
        wt_midh, nullptr, mid_b, mid_g, mid_e, xB, 1024);
    mfma_layer<512, false><<<1024, 256, 0, stream>>>(xB, 512, skip1, 256, 0,
        wt_dec0h, nullptr, dec_b0, dec_g0, dec_e0, xA, 768);
    mfma_layer<256, false><<<1024, 256, 0, stream>>>(xA, 512, skip0, 128, 0,
        wt_dec1h, nullptr, dec_b1, dec_g1, dec_e1, xB, 640);
    outproj_kernel<true><<<8192, 256, 0, stream>>>(xB, out_w, out_b, aq, nullptr);

    // ---------- PASS 2: f32 network via hi/lo MFMA, blended output ----------
    layer0_kernel<false><<<8192, 256, 0, stream>>>(x0, enc_w0, enc_b0, enc_g0, enc_e0, skip0);
    mfma_layer<256, true><<<1024, 256, 0, stream>>>(skip0, 128, nullptr, 0, 0,
        wt_enc1h, wt_enc1l, enc_b1, enc_g1, enc_e1, skip1, 128);
    mfma_layer<512, true><<<1024, 256, 0, stream>>>(skip1, 256, nullptr, 0, 0,
        wt_enc2h, wt_enc2l, enc_b2, enc_g2, enc_e2, xA, 256);
    mfma_layer<512, true><<<1024, 256, 0, stream>>>(xA, 512, temb, 512, 13,
        wt_midh, wt_midl, mid_b, mid_g, mid_e, xB, 1024);
    mfma_layer<512, true><<<1024, 256, 0, stream>>>(xB, 512, skip1, 256, 0,
        wt_dec0h, wt_dec0l, dec_b0, dec_g0, dec_e0, xA, 768);
    mfma_layer<256, true><<<1024, 256, 0, stream>>>(xA, 512, skip0, 128, 0,
        wt_dec1h, wt_dec1l, dec_b1, dec_g1, dec_e1, xB, 640);
    outproj_kernel<false><<<8192, 256, 0, stream>>>(xB, out_w, out_b, aq, (float*)d_out);
}